// Round 1
// baseline (202.208 us; speedup 1.0000x reference)
//
#include <hip/hip_runtime.h>
#include <math.h>

#define DIMH 256        // D
#define NB   32         // batch
#define E_TOT 43234
#define TE   32         // entities per block
#define DK   64         // d-chunk
#define PHASE_SCALE 100.53096491487338   // PI / REL_RANGE = PI / 0.03125

// Kernel 1: rotate head by relation phase. Tiny (32 x 256); double sincos for accuracy.
__global__ void rot_kernel(const float* __restrict__ head,
                           const float* __restrict__ rel,
                           float* __restrict__ rot) {
    int b = blockIdx.x;
    int d = threadIdx.x;
    float re_h = head[b * 2 * DIMH + d];
    float im_h = head[b * 2 * DIMH + DIMH + d];
    // mimic reference: phase rounded to fp32 first, then exact sincos
    float ph_f = rel[b * DIMH + d] * (float)PHASE_SCALE;
    double s, c;
    sincos((double)ph_f, &s, &c);
    float re_r = (float)c, im_r = (float)s;
    rot[b * DIMH + d]             = re_h * re_r - im_h * im_r;   // re_rot
    rot[NB * DIMH + b * DIMH + d] = re_h * im_r + im_h * re_r;   // im_rot
}

__device__ __forceinline__ float cplx_abs(float a, float b) {
    return __builtin_amdgcn_sqrtf(fmaf(a, a, b * b));
}

// Kernel 2: block = 32 entities x 32 batch rows. LDS-staged d-chunks,
// 2b x 2e register tile per thread, float2 (ds_read_b64) LDS reads.
__global__ __launch_bounds__(256) void dist_kernel(const float* __restrict__ ent,
                                                   const float* __restrict__ rot,
                                                   float* __restrict__ out) {
    // +2 pad: stride 66 floats -> bank = (2e + d) % 32, only 2-way aliasing (free),
    // and keeps 8-byte alignment for float2 reads at even d.
    __shared__ float s_er[TE][DK + 2];
    __shared__ float s_ei[TE][DK + 2];
    __shared__ float s_rr[NB][DK + 2];
    __shared__ float s_ri[NB][DK + 2];

    const int tid = threadIdx.x;
    const int eb  = blockIdx.x * TE;
    const int e0  = (tid & 15) * 2;   // entity pair within tile
    const int b0  = (tid >> 4) * 2;   // batch pair

    float acc00 = 0.f, acc01 = 0.f, acc10 = 0.f, acc11 = 0.f;

    for (int dk = 0; dk < DIMH; dk += DK) {
        // ---- stage: 4 arrays x 32 rows x 64 cols = 512 float4 each; 2 float4/thread/array
        #pragma unroll
        for (int qq = 0; qq < 2; ++qq) {
            int q   = tid + qq * 256;      // 0..511
            int row = q >> 4;              // 0..31
            int col = (q & 15) << 2;       // 0..60 step 4
            int er  = min(eb + row, E_TOT - 1);   // clamp tail rows (writes guarded later)
            float4 vre = *reinterpret_cast<const float4*>(&ent[(size_t)er * (2 * DIMH) + dk + col]);
            float4 vim = *reinterpret_cast<const float4*>(&ent[(size_t)er * (2 * DIMH) + DIMH + dk + col]);
            float4 vrr = *reinterpret_cast<const float4*>(&rot[row * DIMH + dk + col]);
            float4 vri = *reinterpret_cast<const float4*>(&rot[NB * DIMH + row * DIMH + dk + col]);
            s_er[row][col + 0] = vre.x; s_er[row][col + 1] = vre.y; s_er[row][col + 2] = vre.z; s_er[row][col + 3] = vre.w;
            s_ei[row][col + 0] = vim.x; s_ei[row][col + 1] = vim.y; s_ei[row][col + 2] = vim.z; s_ei[row][col + 3] = vim.w;
            s_rr[row][col + 0] = vrr.x; s_rr[row][col + 1] = vrr.y; s_rr[row][col + 2] = vrr.z; s_rr[row][col + 3] = vrr.w;
            s_ri[row][col + 0] = vri.x; s_ri[row][col + 1] = vri.y; s_ri[row][col + 2] = vri.z; s_ri[row][col + 3] = vri.w;
        }
        __syncthreads();

        #pragma unroll
        for (int d = 0; d < DK; d += 2) {
            float2 rr0 = *reinterpret_cast<const float2*>(&s_rr[b0    ][d]);
            float2 rr1 = *reinterpret_cast<const float2*>(&s_rr[b0 + 1][d]);
            float2 ri0 = *reinterpret_cast<const float2*>(&s_ri[b0    ][d]);
            float2 ri1 = *reinterpret_cast<const float2*>(&s_ri[b0 + 1][d]);
            float2 er0 = *reinterpret_cast<const float2*>(&s_er[e0    ][d]);
            float2 er1 = *reinterpret_cast<const float2*>(&s_er[e0 + 1][d]);
            float2 ei0 = *reinterpret_cast<const float2*>(&s_ei[e0    ][d]);
            float2 ei1 = *reinterpret_cast<const float2*>(&s_ei[e0 + 1][d]);

            acc00 += cplx_abs(rr0.x - er0.x, ri0.x - ei0.x) + cplx_abs(rr0.y - er0.y, ri0.y - ei0.y);
            acc01 += cplx_abs(rr0.x - er1.x, ri0.x - ei1.x) + cplx_abs(rr0.y - er1.y, ri0.y - ei1.y);
            acc10 += cplx_abs(rr1.x - er0.x, ri1.x - ei0.x) + cplx_abs(rr1.y - er0.y, ri1.y - ei0.y);
            acc11 += cplx_abs(rr1.x - er1.x, ri1.x - ei1.x) + cplx_abs(rr1.y - er1.y, ri1.y - ei1.y);
        }
        __syncthreads();
    }

    const int e = eb + e0;
    if (e + 1 < E_TOT) {
        float2 o0 = make_float2(6.0f - acc00, 6.0f - acc01);
        float2 o1 = make_float2(6.0f - acc10, 6.0f - acc11);
        *reinterpret_cast<float2*>(&out[(size_t)b0 * E_TOT + e])       = o0;  // idx even -> 8B aligned
        *reinterpret_cast<float2*>(&out[(size_t)(b0 + 1) * E_TOT + e]) = o1;  // E_TOT even -> still aligned
    } else if (e < E_TOT) {
        out[(size_t)b0 * E_TOT + e]       = 6.0f - acc00;
        out[(size_t)(b0 + 1) * E_TOT + e] = 6.0f - acc10;
    }
}

extern "C" void kernel_launch(void* const* d_in, const int* in_sizes, int n_in,
                              void* d_out, int out_size, void* d_ws, size_t ws_size,
                              hipStream_t stream) {
    const float* head = (const float*)d_in[0];   // (32, 512)
    const float* rel  = (const float*)d_in[1];   // (32, 256)
    const float* ent  = (const float*)d_in[2];   // (43234, 512)
    float* rot = (float*)d_ws;                   // 2 * 32 * 256 floats = 64 KB

    rot_kernel<<<NB, DIMH, 0, stream>>>(head, rel, rot);

    int nblocks = (E_TOT + TE - 1) / TE;         // 1352
    dist_kernel<<<nblocks, 256, 0, stream>>>(ent, rot, (float*)d_out);
}

// Round 2
// 179.788 us; speedup vs baseline: 1.1247x; 1.1247x over previous
//
#include <hip/hip_runtime.h>
#include <math.h>

#define DIMH 256        // D
#define NB   32         // batch
#define E_TOT 43234
#define TE   64         // entities per block
#define DK   32         // d-chunk
#define NCHUNK (DIMH / DK)
// reference: phase = rel / (REL_RANGE/PI); REL_RANGE/PI = 0.03125/PI
#define PHASE_DIV 0.009947183943243459f

typedef float v2f __attribute__((ext_vector_type(2)));

// Kernel 1: rotate head by relation phase. fp32 sincosf (OCML, full range
// reduction) — double sincos was ~90us of software DP emulation on 32 CUs.
__global__ void rot_kernel(const float* __restrict__ head,
                           const float* __restrict__ rel,
                           float* __restrict__ rot) {
    int i = blockIdx.x * blockDim.x + threadIdx.x;   // 0..8191
    int b = i >> 8;
    int d = i & 255;
    float re_h = head[b * 2 * DIMH + d];
    float im_h = head[b * 2 * DIMH + DIMH + d];
    float ph = rel[b * DIMH + d] / PHASE_DIV;        // match reference's division
    float s, c;
    sincosf(ph, &s, &c);
    rot[b * DIMH + d]             = re_h * c - im_h * s;   // re_rot
    rot[NB * DIMH + b * DIMH + d] = re_h * s + im_h * c;   // im_rot
}

__device__ __forceinline__ v2f sqrt2(v2f s) {
    v2f r;
    r.x = __builtin_amdgcn_sqrtf(s.x);
    r.y = __builtin_amdgcn_sqrtf(s.y);
    return r;
}

// Kernel 2: block = 32 batch x 64 entities. Each thread: 2 batch x 4 entity
// accumulators, d packed 2-wide (v_pk_fma_f32 etc). Entity rows per thread are
// {g, g+16, g+32, g+48} so each ds_read_b64 instruction hits all 32 banks
// exactly once (row stride 34 floats -> bank (2g+d)%32, g=0..15) -> conflict-free.
__global__ __launch_bounds__(256, 5) void dist_kernel(const float* __restrict__ ent,
                                                      const float* __restrict__ rot,
                                                      float* __restrict__ out) {
    __shared__ float s_er[TE][DK + 2];
    __shared__ float s_ei[TE][DK + 2];
    __shared__ float s_rr[NB][DK + 2];
    __shared__ float s_ri[NB][DK + 2];

    const int tid = threadIdx.x;
    const int eb  = blockIdx.x * TE;
    const int g   = tid & 15;         // entity group: rows g + 16k
    const int b0  = (tid >> 4) * 2;   // batch pair

    v2f acc0[4], acc1[4];
    #pragma unroll
    for (int k = 0; k < 4; ++k) {
        acc0[k].x = 0.f; acc0[k].y = 0.f;
        acc1[k].x = 0.f; acc1[k].y = 0.f;
    }

    for (int c = 0; c < NCHUNK; ++c) {
        const int dk = c * DK;
        // ---- stage entities: 2 arrays x 64 rows x 32 cols = 512 float4 each
        #pragma unroll
        for (int qq = 0; qq < 2; ++qq) {
            int q   = tid + qq * 256;      // 0..511
            int row = q >> 3;              // 0..63
            int col = (q & 7) << 2;        // 0..28
            int er  = eb + row;
            if (er >= E_TOT) er = E_TOT - 1;   // clamp tail (stores guarded later)
            float4 vre = *reinterpret_cast<const float4*>(&ent[(size_t)er * (2 * DIMH) + dk + col]);
            float4 vim = *reinterpret_cast<const float4*>(&ent[(size_t)er * (2 * DIMH) + DIMH + dk + col]);
            *reinterpret_cast<float2*>(&s_er[row][col])     = make_float2(vre.x, vre.y);
            *reinterpret_cast<float2*>(&s_er[row][col + 2]) = make_float2(vre.z, vre.w);
            *reinterpret_cast<float2*>(&s_ei[row][col])     = make_float2(vim.x, vim.y);
            *reinterpret_cast<float2*>(&s_ei[row][col + 2]) = make_float2(vim.z, vim.w);
        }
        // ---- stage rot: 2 arrays x 32 rows x 32 cols = 256 float4 each
        {
            int row = tid >> 3;            // 0..31
            int col = (tid & 7) << 2;      // 0..28
            float4 vrr = *reinterpret_cast<const float4*>(&rot[row * DIMH + dk + col]);
            float4 vri = *reinterpret_cast<const float4*>(&rot[NB * DIMH + row * DIMH + dk + col]);
            *reinterpret_cast<float2*>(&s_rr[row][col])     = make_float2(vrr.x, vrr.y);
            *reinterpret_cast<float2*>(&s_rr[row][col + 2]) = make_float2(vrr.z, vrr.w);
            *reinterpret_cast<float2*>(&s_ri[row][col])     = make_float2(vri.x, vri.y);
            *reinterpret_cast<float2*>(&s_ri[row][col + 2]) = make_float2(vri.z, vri.w);
        }
        __syncthreads();

        #pragma unroll 2
        for (int d = 0; d < DK; d += 2) {
            v2f rr0 = *reinterpret_cast<const v2f*>(&s_rr[b0    ][d]);
            v2f rr1 = *reinterpret_cast<const v2f*>(&s_rr[b0 + 1][d]);
            v2f ri0 = *reinterpret_cast<const v2f*>(&s_ri[b0    ][d]);
            v2f ri1 = *reinterpret_cast<const v2f*>(&s_ri[b0 + 1][d]);
            #pragma unroll
            for (int k = 0; k < 4; ++k) {
                v2f er = *reinterpret_cast<const v2f*>(&s_er[g + 16 * k][d]);
                v2f ei = *reinterpret_cast<const v2f*>(&s_ei[g + 16 * k][d]);
                v2f a0 = rr0 - er, c0 = ri0 - ei;
                v2f a1 = rr1 - er, c1 = ri1 - ei;
                v2f s0 = a0 * a0 + c0 * c0;    // v_pk_mul + v_pk_fma
                v2f s1 = a1 * a1 + c1 * c1;
                acc0[k] += sqrt2(s0);
                acc1[k] += sqrt2(s1);
            }
        }
        __syncthreads();
    }

    #pragma unroll
    for (int k = 0; k < 4; ++k) {
        int e = eb + g + 16 * k;
        if (e < E_TOT) {
            out[(size_t)b0 * E_TOT + e]       = 6.0f - (acc0[k].x + acc0[k].y);
            out[(size_t)(b0 + 1) * E_TOT + e] = 6.0f - (acc1[k].x + acc1[k].y);
        }
    }
}

extern "C" void kernel_launch(void* const* d_in, const int* in_sizes, int n_in,
                              void* d_out, int out_size, void* d_ws, size_t ws_size,
                              hipStream_t stream) {
    const float* head = (const float*)d_in[0];   // (32, 512)
    const float* rel  = (const float*)d_in[1];   // (32, 256)
    const float* ent  = (const float*)d_in[2];   // (43234, 512)
    float* rot = (float*)d_ws;                   // 2 * 32 * 256 floats = 64 KB

    rot_kernel<<<(NB * DIMH) / 256, 256, 0, stream>>>(head, rel, rot);

    int nblocks = (E_TOT + TE - 1) / TE;         // 676
    dist_kernel<<<nblocks, 256, 0, stream>>>(ent, rot, (float*)d_out);
}

// Round 3
// 176.518 us; speedup vs baseline: 1.1455x; 1.0185x over previous
//
#include <hip/hip_runtime.h>
#include <math.h>

#define DIMH 256        // D
#define NB   32         // batch
#define E_TOT 43234
#define TE   128        // entities per block
#define DK   32         // d-chunk staged in LDS
#define DHALF 128       // d-range per block (d-split by 2)
// reference: phase = rel / (REL_RANGE/PI); REL_RANGE/PI = 0.03125/PI
#define PHASE_DIV 0.009947183943243459f

typedef float v2f __attribute__((ext_vector_type(2)));

// Kernel 0: out = MARGIN everywhere; dist halves subtract via atomics.
__global__ __launch_bounds__(256) void init_kernel(float* __restrict__ out) {
    int i = blockIdx.x * 256 + threadIdx.x;
    if (i < (NB * E_TOT) / 4) {
        float4 v = make_float4(6.0f, 6.0f, 6.0f, 6.0f);
        reinterpret_cast<float4*>(out)[i] = v;
    }
}

// Kernel 1: rotate head by relation phase (fp32 sincosf).
__global__ void rot_kernel(const float* __restrict__ head,
                           const float* __restrict__ rel,
                           float* __restrict__ rot) {
    int i = blockIdx.x * blockDim.x + threadIdx.x;   // 0..8191
    int b = i >> 8;
    int d = i & 255;
    float re_h = head[b * 2 * DIMH + d];
    float im_h = head[b * 2 * DIMH + DIMH + d];
    float ph = rel[b * DIMH + d] / PHASE_DIV;
    float s, c;
    sincosf(ph, &s, &c);
    rot[b * DIMH + d]             = re_h * c - im_h * s;   // re_rot
    rot[NB * DIMH + b * DIMH + d] = re_h * s + im_h * c;   // im_rot
}

__device__ __forceinline__ v2f sqrt2(v2f s) {
    v2f r;
    r.x = __builtin_amdgcn_sqrtf(s.x);
    r.y = __builtin_amdgcn_sqrtf(s.y);
    return r;
}

// Kernel 2: block = one 128-entity tile x one 128-d half, all 32 batches.
// Per-thread register tile: 4 batch x 4 entity (16 partial sums).
// LDS rows stride DK+2=34 floats: ent-read bank = (2*eg+d)%32, 2 words/bank
// = ds_read_b64 minimum; measured 0 conflicts with this family in R2.
__global__ __launch_bounds__(256, 4) void dist_kernel(const float* __restrict__ ent,
                                                      const float* __restrict__ rot,
                                                      float* __restrict__ out) {
    __shared__ float s_er[TE][DK + 2];
    __shared__ float s_ei[TE][DK + 2];
    __shared__ float s_rr[NB][DK + 2];
    __shared__ float s_ri[NB][DK + 2];

    const int tid   = threadIdx.x;
    const int etile = blockIdx.x >> 1;
    const int half  = blockIdx.x & 1;
    const int eb    = etile * TE;
    const int eg    = tid & 31;          // entity group: rows eg + 32k
    const int bg    = (tid >> 5) * 4;    // first of 4 batch rows
    const int dbase = half * DHALF;

    v2f acc[4][4];   // [batch j][entity k]
    #pragma unroll
    for (int j = 0; j < 4; ++j)
        #pragma unroll
        for (int k = 0; k < 4; ++k) { acc[j][k].x = 0.f; acc[j][k].y = 0.f; }

    for (int c = 0; c < DHALF / DK; ++c) {
        const int dk = dbase + c * DK;
        // ---- stage entities: 2 arrays x 128 rows x 32 cols = 1024 float4 each
        #pragma unroll
        for (int it = 0; it < 4; ++it) {
            int q   = tid + it * 256;      // 0..1023
            int row = q >> 3;              // 0..127
            int col = (q & 7) << 2;        // 0..28
            int er  = eb + row;
            if (er >= E_TOT) er = E_TOT - 1;   // clamp tail (stores guarded later)
            const float* base = &ent[(size_t)er * (2 * DIMH)];
            float4 vre = *reinterpret_cast<const float4*>(base + dk + col);
            float4 vim = *reinterpret_cast<const float4*>(base + DIMH + dk + col);
            *reinterpret_cast<float2*>(&s_er[row][col])     = make_float2(vre.x, vre.y);
            *reinterpret_cast<float2*>(&s_er[row][col + 2]) = make_float2(vre.z, vre.w);
            *reinterpret_cast<float2*>(&s_ei[row][col])     = make_float2(vim.x, vim.y);
            *reinterpret_cast<float2*>(&s_ei[row][col + 2]) = make_float2(vim.z, vim.w);
        }
        // ---- stage rot: 2 arrays x 32 rows x 32 cols = 256 float4 each
        {
            int row = tid >> 3;            // 0..31
            int col = (tid & 7) << 2;      // 0..28
            float4 vrr = *reinterpret_cast<const float4*>(&rot[row * DIMH + dk + col]);
            float4 vri = *reinterpret_cast<const float4*>(&rot[NB * DIMH + row * DIMH + dk + col]);
            *reinterpret_cast<float2*>(&s_rr[row][col])     = make_float2(vrr.x, vrr.y);
            *reinterpret_cast<float2*>(&s_rr[row][col + 2]) = make_float2(vrr.z, vrr.w);
            *reinterpret_cast<float2*>(&s_ri[row][col])     = make_float2(vri.x, vri.y);
            *reinterpret_cast<float2*>(&s_ri[row][col + 2]) = make_float2(vri.z, vri.w);
        }
        __syncthreads();

        #pragma unroll 2
        for (int d = 0; d < DK; d += 2) {
            v2f rr[4], ri[4], er[4], ei[4];
            #pragma unroll
            for (int j = 0; j < 4; ++j) {
                rr[j] = *reinterpret_cast<const v2f*>(&s_rr[bg + j][d]);
                ri[j] = *reinterpret_cast<const v2f*>(&s_ri[bg + j][d]);
            }
            #pragma unroll
            for (int k = 0; k < 4; ++k) {
                er[k] = *reinterpret_cast<const v2f*>(&s_er[eg + 32 * k][d]);
                ei[k] = *reinterpret_cast<const v2f*>(&s_ei[eg + 32 * k][d]);
            }
            #pragma unroll
            for (int j = 0; j < 4; ++j)
                #pragma unroll
                for (int k = 0; k < 4; ++k) {
                    v2f a = rr[j] - er[k];
                    v2f b = ri[j] - ei[k];
                    v2f s = a * a + b * b;     // v_pk_mul + v_pk_fma
                    acc[j][k] += sqrt2(s);     // v_pk_add
                }
        }
        __syncthreads();
    }

    #pragma unroll
    for (int k = 0; k < 4; ++k) {
        int e = eb + eg + 32 * k;
        if (e < E_TOT) {
            #pragma unroll
            for (int j = 0; j < 4; ++j)
                atomicAdd(&out[(size_t)(bg + j) * E_TOT + e],
                          -(acc[j][k].x + acc[j][k].y));
        }
    }
}

extern "C" void kernel_launch(void* const* d_in, const int* in_sizes, int n_in,
                              void* d_out, int out_size, void* d_ws, size_t ws_size,
                              hipStream_t stream) {
    const float* head = (const float*)d_in[0];   // (32, 512)
    const float* rel  = (const float*)d_in[1];   // (32, 256)
    const float* ent  = (const float*)d_in[2];   // (43234, 512)
    float* rot = (float*)d_ws;                   // 2 * 32 * 256 floats = 64 KB

    int init_blocks = ((NB * E_TOT) / 4 + 255) / 256;   // 1352
    init_kernel<<<init_blocks, 256, 0, stream>>>((float*)d_out);
    rot_kernel<<<(NB * DIMH) / 256, 256, 0, stream>>>(head, rel, rot);

    int etiles = (E_TOT + TE - 1) / TE;          // 338
    dist_kernel<<<etiles * 2, 256, 0, stream>>>(ent, rot, (float*)d_out);
}